// Round 2
// baseline (522.139 us; speedup 1.0000x reference)
//
#include <hip/hip_runtime.h>
#include <hip/hip_bf16.h>

// Pipeline (all fp32):
//   agg = D^-1/2 (A+I) D^-1/2 X        (aggregate in F_IN=128 space -- halves gather bytes)
//   out = agg @ W + b                  (fused: column sum/sumsq for BN stats + row-0 capture;
//                                       the [N,256] matrix is never materialized)
//   finalize: BN(row0) -> relu -> proj -> scores   (single tiny block)
//
// CSR-by-dst built per call (histogram -> 2-level exclusive scan -> counting scatter).
// Two execution paths chosen by ws_size at launch (constant across calls, graph-safe):
//   split: agg buffer in workspace (needs ~59 MB)  -- higher-occupancy gather phase
//   fused: aggregation directly into GEMM LDS A-tile (needs ~8.4 MB)
// All index-derived addresses are bounds-clamped so bad inputs cannot fault.

#define THREADS 256

// ---------------- degree histogram ----------------
__global__ __launch_bounds__(THREADS) void deg_kernel(const int* __restrict__ ei,
                                                      int* __restrict__ deg, int E, int N) {
    int e = blockIdx.x * THREADS + threadIdx.x;
    if (e < E) {
        unsigned d = (unsigned)ei[E + e];          // dst row of edge_index
        if (d < (unsigned)N) atomicAdd(&deg[d], 1);
    }
}

// ---------------- dinv = rsqrt(deg + 1)  (+1 self loop) ----------------
__global__ __launch_bounds__(THREADS) void dinv_kernel(const int* __restrict__ deg,
                                                       float* __restrict__ dinv, int n) {
    int i = blockIdx.x * THREADS + threadIdx.x;
    if (i < n) dinv[i] = rsqrtf((float)(deg[i] + 1));
}

// ---------------- exclusive scan, phase 1: per-1024-chunk ----------------
__global__ __launch_bounds__(THREADS) void scan1_kernel(const int* __restrict__ deg,
                                                        int* __restrict__ rowptr,
                                                        int* __restrict__ bsum, int n) {
    __shared__ int sh[THREADS];
    const int t = threadIdx.x, b = blockIdx.x;
    const int base = b * 1024 + t * 4;
    int v0 = (base + 0 < n) ? deg[base + 0] : 0;
    int v1 = (base + 1 < n) ? deg[base + 1] : 0;
    int v2 = (base + 2 < n) ? deg[base + 2] : 0;
    int v3 = (base + 3 < n) ? deg[base + 3] : 0;
    const int local = v0 + v1 + v2 + v3;
    sh[t] = local;
    __syncthreads();
    int run = local;
    for (int off = 1; off < THREADS; off <<= 1) {
        int add = (t >= off) ? sh[t - off] : 0;
        __syncthreads();
        run += add;
        sh[t] = run;
        __syncthreads();
    }
    const int excl = run - local;
    if (base + 0 < n) rowptr[base + 0] = excl;
    if (base + 1 < n) rowptr[base + 1] = excl + v0;
    if (base + 2 < n) rowptr[base + 2] = excl + v0 + v1;
    if (base + 3 < n) rowptr[base + 3] = excl + v0 + v1 + v2;
    if (t == 0) bsum[b] = sh[THREADS - 1];
}

// ---------------- exclusive scan, phase 2: chunk totals (single block) ----------------
__global__ __launch_bounds__(THREADS) void scan2_kernel(const int* __restrict__ bsum,
                                                        int* __restrict__ boff, int nb) {
    __shared__ int sh[THREADS];
    const int t = threadIdx.x;
    const int local = (t < nb) ? bsum[t] : 0;
    sh[t] = local;
    __syncthreads();
    int run = local;
    for (int off = 1; off < THREADS; off <<= 1) {
        int add = (t >= off) ? sh[t - off] : 0;
        __syncthreads();
        run += add;
        sh[t] = run;
        __syncthreads();
    }
    boff[t] = run - local;
}

// ---------------- scan phase 3: add chunk offsets, copy to cursor ----------------
__global__ __launch_bounds__(THREADS) void scan3_kernel(int* __restrict__ rowptr,
                                                        int* __restrict__ cursor,
                                                        const int* __restrict__ boff,
                                                        int n, int E) {
    int i = blockIdx.x * THREADS + threadIdx.x;
    if (i < n) {
        int v = rowptr[i] + boff[i >> 10];
        rowptr[i] = v;
        cursor[i] = v;
    }
    if (i == 0) rowptr[n] = E;
}

// ---------------- counting-sort scatter: build csr_src ----------------
__global__ __launch_bounds__(THREADS) void scatter_kernel(const int* __restrict__ ei,
                                                          int* __restrict__ cursor,
                                                          int* __restrict__ csr,
                                                          int E, int N) {
    int e = blockIdx.x * THREADS + threadIdx.x;
    if (e < E) {
        unsigned d = (unsigned)ei[E + e];
        if (d < (unsigned)N) {
            int p = atomicAdd(&cursor[d], 1);
            if ((unsigned)p < (unsigned)E) csr[p] = ei[e];
        }
    }
}

// ---------------- aggregation core (one wave per dst node row) ----------------
// returns the node's aggregated float2 at feature [lane*2, lane*2+1]
__device__ __forceinline__ float2 agg_row(const float* __restrict__ x,
                                          const int* __restrict__ rowptr,
                                          const int* __restrict__ csr,
                                          const float* __restrict__ dinv,
                                          int i, int n, int lane) {
    const int e0 = rowptr[i], e1 = rowptr[i + 1];
    const float di = dinv[i];
    const float2 xs = *(const float2*)(x + (size_t)i * 128 + lane * 2);
    float ax = di * xs.x, ay = di * xs.y;       // self-loop term (inner)
    int e = e0;
    for (; e + 4 <= e1; e += 4) {               // 4-way batched to break the load chain
        int s0 = csr[e],     s1 = csr[e + 1], s2 = csr[e + 2], s3 = csr[e + 3];
        s0 = ((unsigned)s0 < (unsigned)n) ? s0 : 0;
        s1 = ((unsigned)s1 < (unsigned)n) ? s1 : 0;
        s2 = ((unsigned)s2 < (unsigned)n) ? s2 : 0;
        s3 = ((unsigned)s3 < (unsigned)n) ? s3 : 0;
        float w0 = dinv[s0], w1 = dinv[s1], w2 = dinv[s2], w3 = dinv[s3];
        float2 p0 = *(const float2*)(x + (size_t)s0 * 128 + lane * 2);
        float2 p1 = *(const float2*)(x + (size_t)s1 * 128 + lane * 2);
        float2 p2 = *(const float2*)(x + (size_t)s2 * 128 + lane * 2);
        float2 p3 = *(const float2*)(x + (size_t)s3 * 128 + lane * 2);
        ax = fmaf(w0, p0.x, ax); ay = fmaf(w0, p0.y, ay);
        ax = fmaf(w1, p1.x, ax); ay = fmaf(w1, p1.y, ay);
        ax = fmaf(w2, p2.x, ax); ay = fmaf(w2, p2.y, ay);
        ax = fmaf(w3, p3.x, ax); ay = fmaf(w3, p3.y, ay);
    }
    for (; e < e1; ++e) {
        int s = csr[e];
        s = ((unsigned)s < (unsigned)n) ? s : 0;
        float w = dinv[s];
        float2 p = *(const float2*)(x + (size_t)s * 128 + lane * 2);
        ax = fmaf(w, p.x, ax); ay = fmaf(w, p.y, ay);
    }
    return make_float2(di * ax, di * ay);
}

// ---------------- standalone aggregation (split path) ----------------
__global__ __launch_bounds__(THREADS) void agg_kernel(const float* __restrict__ x,
                                                      const int* __restrict__ rowptr,
                                                      const int* __restrict__ csr,
                                                      const float* __restrict__ dinv,
                                                      float* __restrict__ agg, int n) {
    const int lane = threadIdx.x & 63;
    const int wid  = blockIdx.x * (THREADS >> 6) + (threadIdx.x >> 6);
    const int nw   = gridDim.x * (THREADS >> 6);
    for (int i = wid; i < n; i += nw) {
        float2 o = agg_row(x, rowptr, csr, dinv, i, n, lane);
        *(float2*)(agg + (size_t)i * 128 + lane * 2) = o;
    }
}

// ---------------- shared GEMM epilogue: bias, row0, BN stats ----------------
__device__ __forceinline__ void gemm_epilogue(float acc[4][16], float* red,
                                              const float* __restrict__ bias,
                                              float* __restrict__ colsum,
                                              float* __restrict__ colsumsq,
                                              float* __restrict__ row0,
                                              int rowbase, int n, int tx, int ty, int t,
                                              int blockIdx_x) {
    bool valid[4];
#pragma unroll
    for (int i = 0; i < 4; ++i) valid[i] = (rowbase + ty * 4 + i) < n;
#pragma unroll
    for (int j = 0; j < 16; ++j) {
        float bj = bias[tx * 16 + j];
#pragma unroll
        for (int i = 0; i < 4; ++i)
            if (valid[i]) acc[i][j] += bj;
    }
    if (blockIdx_x == 0 && ty == 0) {
#pragma unroll
        for (int j = 0; j < 16; ++j) row0[tx * 16 + j] = acc[0][j];
    }
    float s[16], q[16];
#pragma unroll
    for (int j = 0; j < 16; ++j) {
        s[j] = 0.f; q[j] = 0.f;
#pragma unroll
        for (int i = 0; i < 4; ++i) {
            s[j] += acc[i][j];
            q[j] = fmaf(acc[i][j], acc[i][j], q[j]);
        }
    }
    float* redS = red;              // 16x256 floats
    float* redQ = red + 16 * 256;   // 16x256 floats (32 KB total)
#pragma unroll
    for (int j = 0; j < 16; ++j) {
        redS[ty * 256 + tx * 16 + j] = s[j];
        redQ[ty * 256 + tx * 16 + j] = q[j];
    }
    __syncthreads();
    float S = 0.f, Q = 0.f;
#pragma unroll
    for (int g = 0; g < 16; ++g) {
        S += redS[g * 256 + t];
        Q += redQ[g * 256 + t];
    }
    atomicAdd(&colsum[t], S);
    atomicAdd(&colsumsq[t], Q);
}

// ---------------- split path GEMM: A from global, fused stats ----------------
// block: 64 rows x 256 cols, 256 threads (16x16), thread: 4 rows x 16 cols.
__global__ __launch_bounds__(THREADS) void gemm_stats_kernel(
        const float* __restrict__ A, const float* __restrict__ W,
        const float* __restrict__ bias, float* __restrict__ colsum,
        float* __restrict__ colsumsq, float* __restrict__ row0, int n) {
    __shared__ float Asm[64 * 36];    // 64 rows x 32 k, stride 36
    __shared__ float Bsm[32 * 320];   // 32 k x 256 cols in 16 blocks of 20 floats (80B)
    const int t = threadIdx.x;
    const int tx = t & 15, ty = t >> 4;
    const int rowbase = blockIdx.x * 64;

    float acc[4][16];
#pragma unroll
    for (int i = 0; i < 4; ++i)
#pragma unroll
        for (int j = 0; j < 16; ++j) acc[i][j] = 0.0f;

    for (int kk = 0; kk < 128; kk += 32) {
#pragma unroll
        for (int u = 0; u < 2; ++u) {           // stage A tile (zero-fill rows past n)
            int f4 = t * 2 + u;                 // 0..511
            int r = f4 >> 3, c4 = f4 & 7;
            int gr = rowbase + r;
            float4 v = make_float4(0.f, 0.f, 0.f, 0.f);
            if (gr < n) v = *(const float4*)(A + (size_t)gr * 128 + kk + c4 * 4);
            *(float4*)(Asm + r * 36 + c4 * 4) = v;
        }
#pragma unroll
        for (int u = 0; u < 8; ++u) {           // stage B tile (80B col-block swizzle)
            int f4 = t + u * 256;               // 0..2047
            int k = f4 >> 6, c4 = f4 & 63;
            float4 v = *(const float4*)(W + (size_t)(kk + k) * 256 + c4 * 4);
            int blk = c4 >> 2, l = (c4 & 3) * 4;
            *(float4*)(Bsm + k * 320 + blk * 20 + l) = v;
        }
        __syncthreads();
#pragma unroll 4
        for (int k = 0; k < 32; ++k) {
            float a[4];
#pragma unroll
            for (int i = 0; i < 4; ++i) a[i] = Asm[(ty * 4 + i) * 36 + k];
            const float* bp = Bsm + k * 320 + tx * 20;
            float4 b0 = *(const float4*)(bp);
            float4 b1 = *(const float4*)(bp + 4);
            float4 b2 = *(const float4*)(bp + 8);
            float4 b3 = *(const float4*)(bp + 12);
            float bb[16] = {b0.x, b0.y, b0.z, b0.w, b1.x, b1.y, b1.z, b1.w,
                            b2.x, b2.y, b2.z, b2.w, b3.x, b3.y, b3.z, b3.w};
#pragma unroll
            for (int i = 0; i < 4; ++i)
#pragma unroll
                for (int j = 0; j < 16; ++j) acc[i][j] = fmaf(a[i], bb[j], acc[i][j]);
        }
        __syncthreads();
    }
    gemm_epilogue(acc, Bsm, bias, colsum, colsumsq, row0, rowbase, n, tx, ty, t,
                  blockIdx.x);
}

// ---------------- fused path: aggregate into LDS A-tile, then GEMM ----------------
__global__ __launch_bounds__(THREADS) void fused_agg_gemm_kernel(
        const float* __restrict__ x, const int* __restrict__ rowptr,
        const int* __restrict__ csr, const float* __restrict__ dinv,
        const float* __restrict__ W, const float* __restrict__ bias,
        float* __restrict__ colsum, float* __restrict__ colsumsq,
        float* __restrict__ row0, int n) {
    __shared__ float Asm[64 * 132];   // full 64 rows x 128 k, stride 132 (33 KB)
    __shared__ float Bsm[16 * 320];   // 16 k x 256 cols, 80B col-blocks (20 KB)
    const int t = threadIdx.x;
    const int lane = t & 63, wv = t >> 6;
    const int tx = t & 15, ty = t >> 4;
    const int rowbase = blockIdx.x * 64;

    // phase 1: each wave aggregates 16 rows into Asm
    for (int rr = 0; rr < 16; ++rr) {
        const int r = wv * 16 + rr;
        const int i = rowbase + r;
        float2 o = make_float2(0.f, 0.f);
        if (i < n) o = agg_row(x, rowptr, csr, dinv, i, n, lane);
        *(float2*)(Asm + r * 132 + lane * 2) = o;
    }
    __syncthreads();

    // phase 2: GEMM, B staged in 16-k chunks
    float acc[4][16];
#pragma unroll
    for (int i = 0; i < 4; ++i)
#pragma unroll
        for (int j = 0; j < 16; ++j) acc[i][j] = 0.0f;

    for (int kk = 0; kk < 128; kk += 16) {
#pragma unroll
        for (int u = 0; u < 4; ++u) {
            int f4 = t + u * 256;               // 0..1023
            int k = f4 >> 6, c4 = f4 & 63;
            float4 v = *(const float4*)(W + (size_t)(kk + k) * 256 + c4 * 4);
            int blk = c4 >> 2, l = (c4 & 3) * 4;
            *(float4*)(Bsm + k * 320 + blk * 20 + l) = v;
        }
        __syncthreads();
#pragma unroll 4
        for (int k = 0; k < 16; ++k) {
            float a[4];
#pragma unroll
            for (int i = 0; i < 4; ++i) a[i] = Asm[(ty * 4 + i) * 132 + kk + k];
            const float* bp = Bsm + k * 320 + tx * 20;
            float4 b0 = *(const float4*)(bp);
            float4 b1 = *(const float4*)(bp + 4);
            float4 b2 = *(const float4*)(bp + 8);
            float4 b3 = *(const float4*)(bp + 12);
            float bb[16] = {b0.x, b0.y, b0.z, b0.w, b1.x, b1.y, b1.z, b1.w,
                            b2.x, b2.y, b2.z, b2.w, b3.x, b3.y, b3.z, b3.w};
#pragma unroll
            for (int i = 0; i < 4; ++i)
#pragma unroll
                for (int j = 0; j < 16; ++j) acc[i][j] = fmaf(a[i], bb[j], acc[i][j]);
        }
        __syncthreads();
    }
    gemm_epilogue(acc, Asm, bias, colsum, colsumsq, row0, rowbase, n, tx, ty, t,
                  blockIdx.x);
}

// ---------------- finalize: BN(row0)+relu -> proj -> scores ----------------
__global__ __launch_bounds__(THREADS) void finalize_kernel(
        const float* __restrict__ colsum, const float* __restrict__ colsumsq,
        const float* __restrict__ row0, const float* __restrict__ gamma,
        const float* __restrict__ beta, const float* __restrict__ proj_w,
        const float* __restrict__ proj_b, const float* __restrict__ emb,
        float* __restrict__ out, int n_nodes, int n_items) {
    __shared__ float x0[256];
    __shared__ float rsu[128];
    const int t = threadIdx.x;
    const float invn = 1.0f / (float)n_nodes;
    {
        float mean = colsum[t] * invn;
        float var = colsumsq[t] * invn - mean * mean;
        float r = rsqrtf(var + 1e-5f);
        float v = gamma[t] * (row0[t] - mean) * r + beta[t];
        x0[t] = v > 0.f ? v : 0.f;
    }
    __syncthreads();
    if (t < 128) {
        float sacc = proj_b[t];
        for (int c = 0; c < 256; ++c) sacc = fmaf(x0[c], proj_w[c * 128 + t], sacc);
        rsu[t] = sacc;
        out[128 + t] = sacc;      // rsu_embedding
    }
    __syncthreads();
    if (t < n_items) {
        float sacc = 0.f;
        for (int j = 0; j < 128; ++j) sacc = fmaf(emb[t * 128 + j], rsu[j], sacc);
        out[t] = sacc;            // scores
    }
}

extern "C" void kernel_launch(void* const* d_in, const int* in_sizes, int n_in,
                              void* d_out, int out_size, void* d_ws, size_t ws_size,
                              hipStream_t stream) {
    const float* node_feature = (const float*)d_in[0];
    const int*   edge_index   = (const int*)d_in[1];
    // d_in[2] items_ready_to_cache: unused (reference uses arange(n_items))
    const float* gcn_w  = (const float*)d_in[3];
    const float* gcn_b  = (const float*)d_in[4];
    const float* bn_g   = (const float*)d_in[5];
    const float* bn_b   = (const float*)d_in[6];
    const float* emb    = (const float*)d_in[7];
    const float* proj_w = (const float*)d_in[8];
    const float* proj_b = (const float*)d_in[9];
    float* out = (float*)d_out;

    const int N = in_sizes[0] / 128;
    const int E = in_sizes[1] / 2;
    const int n_items = in_sizes[2];

    // workspace carve (256B aligned)
    char* base = (char*)d_ws;
    size_t off = 0;
    auto alloc = [&](size_t bytes) -> void* {
        void* p = (void*)(base + off);
        off += (bytes + 255) & ~(size_t)255;
        return p;
    };
    int*   deg      = (int*)alloc((size_t)N * 4);
    float* dinv     = (float*)alloc((size_t)N * 4);
    int*   rowptr   = (int*)alloc(((size_t)N + 1) * 4);
    int*   cursor   = (int*)alloc((size_t)N * 4);
    int*   bsum     = (int*)alloc(256 * 4);
    int*   boff     = (int*)alloc(256 * 4);
    float* colsum   = (float*)alloc(256 * 4);
    float* colsumsq = (float*)alloc(256 * 4);   // contiguous after colsum
    float* row0     = (float*)alloc(256 * 4);
    int*   csr      = (int*)alloc((size_t)E * 4);
    const size_t fused_need = off;
    float* agg      = (float*)alloc((size_t)N * 128 * 4);
    const size_t split_need = off;
    const bool use_split = (ws_size >= split_need);
    (void)fused_need;

    const int nbE = (E + THREADS - 1) / THREADS;
    const int nbN = (N + THREADS - 1) / THREADS;
    const int nchunks = (N + 1023) >> 10;       // <= 256 for N <= 262144
    const int nbRow = (N + 63) / 64;

    hipMemsetAsync(deg, 0, (size_t)N * 4, stream);
    hipMemsetAsync(colsum, 0, 2 * 256 * 4, stream);   // colsum + colsumsq

    deg_kernel<<<nbE, THREADS, 0, stream>>>(edge_index, deg, E, N);
    dinv_kernel<<<nbN, THREADS, 0, stream>>>(deg, dinv, N);
    scan1_kernel<<<nchunks, THREADS, 0, stream>>>(deg, rowptr, bsum, N);
    scan2_kernel<<<1, THREADS, 0, stream>>>(bsum, boff, nchunks);
    scan3_kernel<<<nbN, THREADS, 0, stream>>>(rowptr, cursor, boff, N, E);
    scatter_kernel<<<nbE, THREADS, 0, stream>>>(edge_index, cursor, csr, E, N);
    if (use_split) {
        agg_kernel<<<2048, THREADS, 0, stream>>>(node_feature, rowptr, csr, dinv,
                                                 agg, N);
        gemm_stats_kernel<<<nbRow, THREADS, 0, stream>>>(agg, gcn_w, gcn_b,
                                                         colsum, colsumsq, row0, N);
    } else {
        fused_agg_gemm_kernel<<<nbRow, THREADS, 0, stream>>>(node_feature, rowptr,
                                                             csr, dinv, gcn_w, gcn_b,
                                                             colsum, colsumsq, row0, N);
    }
    finalize_kernel<<<1, THREADS, 0, stream>>>(colsum, colsumsq, row0, bn_g, bn_b,
                                               proj_w, proj_b, emb, out, N, n_items);
}

// Round 3
// 421.700 us; speedup vs baseline: 1.2382x; 1.2382x over previous
//
#include <hip/hip_runtime.h>
#include <hip/hip_bf16.h>

// Pipeline (all fp32). Never materializes agg[N,128] nor out[N,256]:
//   G = agg^T agg (128x128 Gram), s = colsum(agg), a0 = agg row0   -- one fused kernel
//   colsum_j   = s.w_j + N b_j
//   colsumsq_j = w_j^T G w_j + 2 b_j (s.w_j) + N b_j^2              -- exact algebra
//   row0_j     = a0.w_j + b_j
//   finalize: BN(row0) -> relu -> proj -> scores
// CSR build: deg+rank pass (atomics once) -> scan -> atomic-free scatter.

#define THREADS 256

// ---------------- degree histogram + per-edge rank ----------------
__global__ __launch_bounds__(THREADS) void deg_rank_kernel(const int* __restrict__ ei,
                                                           int* __restrict__ deg,
                                                           int* __restrict__ rank,
                                                           int E, int N) {
    int e = blockIdx.x * THREADS + threadIdx.x;
    if (e < E) {
        unsigned d = (unsigned)ei[E + e];          // dst row
        int p = 0;
        if (d < (unsigned)N) p = atomicAdd(&deg[d], 1);
        rank[e] = p;
    }
}

// ---------------- scan phase 1 (per-1024 chunk) + dinv ----------------
__global__ __launch_bounds__(THREADS) void scan1_kernel(const int* __restrict__ deg,
                                                        int* __restrict__ rowptr,
                                                        int* __restrict__ bsum,
                                                        float* __restrict__ dinv, int n) {
    __shared__ int sh[THREADS];
    const int t = threadIdx.x, b = blockIdx.x;
    const int base = b * 1024 + t * 4;
    int v0 = (base + 0 < n) ? deg[base + 0] : 0;
    int v1 = (base + 1 < n) ? deg[base + 1] : 0;
    int v2 = (base + 2 < n) ? deg[base + 2] : 0;
    int v3 = (base + 3 < n) ? deg[base + 3] : 0;
    if (base + 0 < n) dinv[base + 0] = rsqrtf((float)(v0 + 1));
    if (base + 1 < n) dinv[base + 1] = rsqrtf((float)(v1 + 1));
    if (base + 2 < n) dinv[base + 2] = rsqrtf((float)(v2 + 1));
    if (base + 3 < n) dinv[base + 3] = rsqrtf((float)(v3 + 1));
    const int local = v0 + v1 + v2 + v3;
    sh[t] = local;
    __syncthreads();
    int run = local;
    for (int off = 1; off < THREADS; off <<= 1) {
        int add = (t >= off) ? sh[t - off] : 0;
        __syncthreads();
        run += add;
        sh[t] = run;
        __syncthreads();
    }
    const int excl = run - local;
    if (base + 0 < n) rowptr[base + 0] = excl;
    if (base + 1 < n) rowptr[base + 1] = excl + v0;
    if (base + 2 < n) rowptr[base + 2] = excl + v0 + v1;
    if (base + 3 < n) rowptr[base + 3] = excl + v0 + v1 + v2;
    if (t == 0) bsum[b] = sh[THREADS - 1];
}

// ---------------- scan phase 2 (chunk offsets) + zero small buffers ----------------
__global__ __launch_bounds__(THREADS) void scan2_kernel(const int* __restrict__ bsum,
                                                        int* __restrict__ boff, int nb,
                                                        float* __restrict__ colsumS,
                                                        float* __restrict__ G,
                                                        int* __restrict__ workctr) {
    __shared__ int sh[THREADS];
    const int t = threadIdx.x;
    const int local = (t < nb) ? bsum[t] : 0;
    sh[t] = local;
    __syncthreads();
    int run = local;
    for (int off = 1; off < THREADS; off <<= 1) {
        int add = (t >= off) ? sh[t - off] : 0;
        __syncthreads();
        run += add;
        sh[t] = run;
        __syncthreads();
    }
    boff[t] = run - local;
    if (t < 128) colsumS[t] = 0.f;
    if (t == 0) *workctr = 0;
    for (int u = t; u < 16384; u += THREADS) G[u] = 0.f;
}

// ---------------- atomic-free counting-sort scatter ----------------
__global__ __launch_bounds__(THREADS) void scatter_kernel(const int* __restrict__ ei,
                                                          const int* __restrict__ rowptr,
                                                          const int* __restrict__ boff,
                                                          const int* __restrict__ rank,
                                                          int* __restrict__ csr,
                                                          int E, int N) {
    int e = blockIdx.x * THREADS + threadIdx.x;
    if (e < E) {
        unsigned d = (unsigned)ei[E + e];
        if (d < (unsigned)N) {
            int base = rowptr[d] + boff[d >> 10] + rank[e];
            if ((unsigned)base < (unsigned)E) csr[base] = ei[e];
        }
    }
}

// ---------------- fused aggregate + Gram (syrk) + colsum + row0 ----------------
// 512 threads. Work-steal 64-row chunks; gather rows into LDS; accumulate
// register-resident G partial (8x4 per thread over 16x32 grid); per-block
// Gpart write at end; s via t<128 column sums.
__global__ __launch_bounds__(512) void agg_syrk_kernel(
        const float* __restrict__ x, const int* __restrict__ rowptr,
        const int* __restrict__ boff, const int* __restrict__ csr,
        const float* __restrict__ dinv, int* __restrict__ workctr,
        float* __restrict__ Gpart, float* __restrict__ colsumS,
        float* __restrict__ agg0, int n, int E, int NC) {
    __shared__ float Asm[64 * 132];   // 64 rows x 128 cols, stride 132 (16B-aligned rows)
    __shared__ int sh_c;
    const int t = threadIdx.x;
    const int lane = t & 63, wv = t >> 6;
    const int p0 = (t >> 5) * 8;      // 16 p-groups x 8
    const int q0 = (t & 31) * 4;      // 32 q-groups x 4
    const float* xl = x + lane * 2;

    float acc[8][4];
#pragma unroll
    for (int i = 0; i < 8; ++i)
#pragma unroll
        for (int j = 0; j < 4; ++j) acc[i][j] = 0.f;
    float s_acc = 0.f;

    for (;;) {
        if (t == 0) sh_c = atomicAdd(workctr, 1);
        __syncthreads();
        const int c = sh_c;
        if (c >= NC) break;

        // gather: wave wv aggregates rows wv*8 .. wv*8+7 of this chunk
        for (int rr = 0; rr < 8; ++rr) {
            const int r = wv * 8 + rr;
            const int i = c * 64 + r;
            float ax = 0.f, ay = 0.f;
            if (i < n) {
                const int e0 = rowptr[i] + boff[i >> 10];
                const int e1 = (i + 1 < n) ? rowptr[i + 1] + boff[(i + 1) >> 10] : E;
                const float di = dinv[i];
                const float2 xs = *(const float2*)(xl + (size_t)i * 128);
                ax = di * xs.x; ay = di * xs.y;           // self-loop (inner)
                int e = e0;
                for (; e + 8 <= e1; e += 8) {             // 8-deep MLP
                    int ss[8]; float ww[8]; float2 pv[8];
#pragma unroll
                    for (int u = 0; u < 8; ++u) {
                        int s = csr[e + u];
                        ss[u] = ((unsigned)s < (unsigned)n) ? s : 0;
                    }
#pragma unroll
                    for (int u = 0; u < 8; ++u) ww[u] = dinv[ss[u]];
#pragma unroll
                    for (int u = 0; u < 8; ++u)
                        pv[u] = *(const float2*)(xl + (size_t)ss[u] * 128);
#pragma unroll
                    for (int u = 0; u < 8; ++u) {
                        ax = fmaf(ww[u], pv[u].x, ax);
                        ay = fmaf(ww[u], pv[u].y, ay);
                    }
                }
                for (; e < e1; ++e) {
                    int s = csr[e];
                    s = ((unsigned)s < (unsigned)n) ? s : 0;
                    float w = dinv[s];
                    float2 p = *(const float2*)(xl + (size_t)s * 128);
                    ax = fmaf(w, p.x, ax);
                    ay = fmaf(w, p.y, ay);
                }
                ax *= di; ay *= di;
            }
            *(float2*)(Asm + r * 132 + lane * 2) = make_float2(ax, ay);
        }
        __syncthreads();

        if (c == 0 && t < 32)
            *(float4*)(agg0 + t * 4) = *(const float4*)(Asm + t * 4);

        // syrk: G += Asm^T Asm  (inner dim = 64 rows)
#pragma unroll 4
        for (int r = 0; r < 64; ++r) {
            const float* row = Asm + r * 132;
            float4 a0 = *(const float4*)(row + p0);
            float4 a1 = *(const float4*)(row + p0 + 4);
            float4 bq = *(const float4*)(row + q0);
            float ap[8] = {a0.x, a0.y, a0.z, a0.w, a1.x, a1.y, a1.z, a1.w};
            float aq[4] = {bq.x, bq.y, bq.z, bq.w};
#pragma unroll
            for (int pp = 0; pp < 8; ++pp)
#pragma unroll
                for (int qq = 0; qq < 4; ++qq)
                    acc[pp][qq] = fmaf(ap[pp], aq[qq], acc[pp][qq]);
        }
        if (t < 128) {   // column sums for s
            float sa = 0.f;
            for (int r = 0; r < 64; ++r) sa += Asm[r * 132 + t];
            s_acc += sa;
        }
        __syncthreads();
    }

    float* gp = Gpart + (size_t)blockIdx.x * 16384;
#pragma unroll
    for (int pp = 0; pp < 8; ++pp)
        *(float4*)(gp + (p0 + pp) * 128 + q0) =
            make_float4(acc[pp][0], acc[pp][1], acc[pp][2], acc[pp][3]);
    if (t < 128) atomicAdd(&colsumS[t], s_acc);
}

// ---------------- reduce Gpart -> G (8 segments, atomic combine) ----------------
__global__ __launch_bounds__(THREADS) void greduce_kernel(const float* __restrict__ Gpart,
                                                          float* __restrict__ G, int NB) {
    const int seg = blockIdx.x >> 4;                       // 8 segments
    const int i4 = (blockIdx.x & 15) * THREADS + threadIdx.x;   // 0..4095
    const int b0 = (seg * NB) / 8, b1 = ((seg + 1) * NB) / 8;
    float4 a = make_float4(0.f, 0.f, 0.f, 0.f);
    for (int b = b0; b < b1; ++b) {
        float4 v = *(const float4*)(Gpart + (size_t)b * 16384 + i4 * 4);
        a.x += v.x; a.y += v.y; a.z += v.z; a.w += v.w;
    }
    atomicAdd(&G[i4 * 4 + 0], a.x);
    atomicAdd(&G[i4 * 4 + 1], a.y);
    atomicAdd(&G[i4 * 4 + 2], a.z);
    atomicAdd(&G[i4 * 4 + 3], a.w);
}

// ---------------- per-column stats from G, s, agg0 (one block per j) ----------------
__global__ __launch_bounds__(THREADS) void stats_kernel(
        const float* __restrict__ G, const float* __restrict__ W,
        const float* __restrict__ bias, const float* __restrict__ colsumS,
        const float* __restrict__ agg0, float* __restrict__ colsum,
        float* __restrict__ colsumsq, float* __restrict__ row0, int n) {
    __shared__ float wsm[128];
    __shared__ float red[THREADS], red2[THREADS], red3[THREADS];
    const int t = threadIdx.x, j = blockIdx.x;
    if (t < 128) wsm[t] = W[t * 256 + j];
    __syncthreads();
    float part = 0.f;
    const float wq = wsm[t & 127];
    const int pbase = t >> 7;          // 0 or 1
#pragma unroll 8
    for (int u = 0; u < 64; ++u)       // f = u*256 + t, coalesced
        part = fmaf(G[u * 256 + t], wsm[pbase + u * 2], part);
    red[t] = part * wq;
    red2[t] = (t < 128) ? colsumS[t] * wsm[t] : 0.f;
    red3[t] = (t < 128) ? agg0[t] * wsm[t] : 0.f;
    __syncthreads();
    for (int s = 128; s > 0; s >>= 1) {
        if (t < s) { red[t] += red[t + s]; red2[t] += red2[t + s]; red3[t] += red3[t + s]; }
        __syncthreads();
    }
    if (t == 0) {
        const float b = bias[j];
        const float sw = red2[0];
        colsum[j]   = sw + (float)n * b;
        colsumsq[j] = red[0] + 2.f * b * sw + (float)n * b * b;
        row0[j]     = red3[0] + b;
    }
}

// ---------------- finalize: BN(row0)+relu -> proj -> scores ----------------
__global__ __launch_bounds__(THREADS) void finalize_kernel(
        const float* __restrict__ colsum, const float* __restrict__ colsumsq,
        const float* __restrict__ row0, const float* __restrict__ gamma,
        const float* __restrict__ beta, const float* __restrict__ proj_w,
        const float* __restrict__ proj_b, const float* __restrict__ emb,
        float* __restrict__ out, int n_nodes, int n_items) {
    __shared__ float x0[256];
    __shared__ float rsu[128];
    const int t = threadIdx.x;
    const float invn = 1.0f / (float)n_nodes;
    {
        float mean = colsum[t] * invn;
        float var = colsumsq[t] * invn - mean * mean;
        float r = rsqrtf(var + 1e-5f);
        float v = gamma[t] * (row0[t] - mean) * r + beta[t];
        x0[t] = v > 0.f ? v : 0.f;
    }
    __syncthreads();
    if (t < 128) {
        float sacc = proj_b[t];
        for (int c = 0; c < 256; ++c) sacc = fmaf(x0[c], proj_w[c * 128 + t], sacc);
        rsu[t] = sacc;
        out[128 + t] = sacc;      // rsu_embedding
    }
    __syncthreads();
    if (t < n_items) {
        float sacc = 0.f;
        for (int j = 0; j < 128; ++j) sacc = fmaf(emb[t * 128 + j], rsu[j], sacc);
        out[t] = sacc;            // scores
    }
}

extern "C" void kernel_launch(void* const* d_in, const int* in_sizes, int n_in,
                              void* d_out, int out_size, void* d_ws, size_t ws_size,
                              hipStream_t stream) {
    const float* node_feature = (const float*)d_in[0];
    const int*   edge_index   = (const int*)d_in[1];
    // d_in[2] items_ready_to_cache: unused (reference uses arange(n_items))
    const float* gcn_w  = (const float*)d_in[3];
    const float* gcn_b  = (const float*)d_in[4];
    const float* bn_g   = (const float*)d_in[5];
    const float* bn_b   = (const float*)d_in[6];
    const float* emb    = (const float*)d_in[7];
    const float* proj_w = (const float*)d_in[8];
    const float* proj_b = (const float*)d_in[9];
    float* out = (float*)d_out;

    const int N = in_sizes[0] / 128;
    const int E = in_sizes[1] / 2;
    const int n_items = in_sizes[2];

    // workspace carve (256B aligned); Gpart last so NB can shrink to fit
    char* base = (char*)d_ws;
    size_t off = 0;
    auto alloc = [&](size_t bytes) -> void* {
        void* p = (void*)(base + off);
        off += (bytes + 255) & ~(size_t)255;
        return p;
    };
    int*   deg      = (int*)alloc((size_t)N * 4);
    int*   rank     = (int*)alloc((size_t)E * 4);
    int*   rowptr   = (int*)alloc((size_t)N * 4);
    int*   bsum     = (int*)alloc(256 * 4);
    int*   boff     = (int*)alloc(256 * 4);
    float* dinv     = (float*)alloc((size_t)N * 4);
    int*   csr      = (int*)alloc((size_t)E * 4);
    float* colsumS  = (float*)alloc(128 * 4);
    float* agg0     = (float*)alloc(128 * 4);
    float* G        = (float*)alloc(16384 * 4);
    float* colsum   = (float*)alloc(256 * 4);
    float* colsumsq = (float*)alloc(256 * 4);
    float* row0     = (float*)alloc(256 * 4);
    int*   workctr  = (int*)alloc(256);
    int NB = (int)((ws_size > off) ? ((ws_size - off) / (16384 * 4)) : 0);
    if (NB > 512) NB = 512;
    if (NB < 8) NB = 8;               // ws is known >= 59 MB; 8 always fits
    float* Gpart    = (float*)alloc((size_t)NB * 16384 * 4);

    const int nbE = (E + THREADS - 1) / THREADS;
    const int nchunks = (N + 1023) >> 10;     // <= 256 for N <= 262144
    const int NC = (N + 63) / 64;

    hipMemsetAsync(deg, 0, (size_t)N * 4, stream);

    deg_rank_kernel<<<nbE, THREADS, 0, stream>>>(edge_index, deg, rank, E, N);
    scan1_kernel<<<nchunks, THREADS, 0, stream>>>(deg, rowptr, bsum, dinv, N);
    scan2_kernel<<<1, THREADS, 0, stream>>>(bsum, boff, nchunks, colsumS, G, workctr);
    scatter_kernel<<<nbE, THREADS, 0, stream>>>(edge_index, rowptr, boff, rank, csr, E, N);
    agg_syrk_kernel<<<NB, 512, 0, stream>>>(node_feature, rowptr, boff, csr, dinv,
                                            workctr, Gpart, colsumS, agg0, N, E, NC);
    greduce_kernel<<<128, THREADS, 0, stream>>>(Gpart, G, NB);
    stats_kernel<<<256, THREADS, 0, stream>>>(G, gcn_w, gcn_b, colsumS, agg0,
                                              colsum, colsumsq, row0, N);
    finalize_kernel<<<1, THREADS, 0, stream>>>(colsum, colsumsq, row0, bn_g, bn_b,
                                               proj_w, proj_b, emb, out, N, n_items);
}